// Round 3
// baseline (479.206 us; speedup 1.0000x reference)
//
#include <hip/hip_runtime.h>

// MultiBoxLoss_four_corners — B=64, P=8732, C=81, NEG_POS_RATIO=3
// Outputs: (loss_l/N, loss_c/N, loss_four_corners/N) -> d_out[0..2] (f32)
//
// R3: conf rows staged tile-wise into LDS via coalesced float4 loads
// (R2 was VMEM-transaction-bound: row-per-thread = 64 lines per load inst).
// CE computed from LDS, 4 threads per row. Per-batch sums via atomics.
// General hard-negative top-K path retained in k_batch (rare).

#define NB 64
#define NP 8732
#define NC 81
constexpr int BP   = NB * NP;                 // 558848
constexpr int ROWS = 64;                      // rows per tile (20736 B LDS)
constexpr int TPB  = (NP + ROWS - 1) / ROWS;  // 137 tiles per batch (tail 44)

__device__ inline float sl1(float d) {
    d = fabsf(d);
    return d < 1.0f ? 0.5f * d * d : d - 0.5f;
}

// ws layout: ce[BP] | acc[2] | npos_b[64](int) | spos_b[64] | sneg_b[64] | loss_c_b[64]
__global__ void k_init(float* acc_area) {
    if (threadIdx.x < 194) acc_area[threadIdx.x] = 0.0f;
}

__global__ __launch_bounds__(256) void k_main(
    const float* __restrict__ loc_data, const float* __restrict__ conf_data,
    const float* __restrict__ fc_data,  const float* __restrict__ loc_t,
    const float* __restrict__ fc_t,     const int* __restrict__ conf_t,
    float* __restrict__ ce, float* __restrict__ acc,
    int* __restrict__ npos_b, float* __restrict__ spos_b, float* __restrict__ sneg_b)
{
    __shared__ float conf_s[ROWS * NC];       // 20736 B
    __shared__ int   tgt_s[ROWS];
    __shared__ float red[4][5];

    const int b    = blockIdx.y;
    const int r0   = blockIdx.x * ROWS;
    const int nrows = min(ROWS, NP - r0);     // 64 or 44 (both %4==0)
    const int t    = threadIdx.x;
    const size_t rowbase = (size_t)b * NP + r0;

    // ---- stage conf tile: fully coalesced float4 (tile start 16B-aligned) ----
    const int nf4 = (nrows * NC) >> 2;        // 1296 or 891
    const float4* src = (const float4*)(conf_data + rowbase * NC);
    for (int i = t; i < nf4; i += 256)
        ((float4*)conf_s)[i] = src[i];

    // ---- per-row: tgt + smooth-L1 (threads t < nrows, coalesced float4) ----
    float l_sum = 0.0f, f_sum = 0.0f;
    int np = 0;
    if (t < nrows) {
        const size_t g = rowbase + t;
        const int tgt = conf_t[g];
        tgt_s[t] = tgt;
        const float posf = (tgt > 0) ? 1.0f : 0.0f;
        np = (tgt > 0) ? 1 : 0;
        float4 a  = ((const float4*)loc_data)[g];
        float4 at = ((const float4*)loc_t)[g];
        l_sum = (sl1(a.x - at.x) + sl1(a.y - at.y) +
                 sl1(a.z - at.z) + sl1(a.w - at.w)) * posf;
        float4 c0 = ((const float4*)fc_data)[2 * g];
        float4 c1 = ((const float4*)fc_data)[2 * g + 1];
        float4 d0 = ((const float4*)fc_t)[2 * g];
        float4 d1 = ((const float4*)fc_t)[2 * g + 1];
        f_sum = (sl1(c0.x - d0.x) + sl1(c0.y - d0.y) + sl1(c0.z - d0.z) + sl1(c0.w - d0.w) +
                 sl1(c1.x - d1.x) + sl1(c1.y - d1.y) + sl1(c1.z - d1.z) + sl1(c1.w - d1.w)) * posf;
    }
    __syncthreads();

    // ---- CE: 4 threads per row, quarter-columns, combine via shuffles ----
    float sp = 0.0f, sn = 0.0f;
    const int r = t >> 2, q = t & 3;
    if (r < nrows) {
        const float* rowp = conf_s + r * NC;
        const int c0 = q * 20;
        const int c1 = (q == 3) ? NC : c0 + 20;
        float s = 0.0f;
        #pragma unroll 5
        for (int c = c0; c < c1; ++c) s += __expf(rowp[c]);
        s += __shfl_xor(s, 1, 64);
        s += __shfl_xor(s, 2, 64);
        if (q == 0) {
            const int tgt = tgt_s[r];
            const float cev = __logf(s) - rowp[tgt];
            ce[rowbase + r] = cev;
            if (tgt > 0) sp = cev; else sn = cev;
        }
    }

    // ---- block reduce {l, f, sp, sn, np} -> atomics (b uniform per block) ----
    const int wave = t >> 6, lane = t & 63;
    float vnp = (float)np;
    #pragma unroll
    for (int o = 32; o; o >>= 1) {
        l_sum += __shfl_xor(l_sum, o, 64);
        f_sum += __shfl_xor(f_sum, o, 64);
        sp    += __shfl_xor(sp, o, 64);
        sn    += __shfl_xor(sn, o, 64);
        vnp   += __shfl_xor(vnp, o, 64);
    }
    if (lane == 0) {
        red[wave][0] = l_sum; red[wave][1] = f_sum;
        red[wave][2] = sp;    red[wave][3] = sn;   red[wave][4] = vnp;
    }
    __syncthreads();
    if (t == 0) {
        float rl = 0, rf = 0, rp = 0, rn = 0, rc = 0;
        #pragma unroll
        for (int w = 0; w < 4; ++w) {
            rl += red[w][0]; rf += red[w][1]; rp += red[w][2];
            rn += red[w][3]; rc += red[w][4];
        }
        atomicAdd(&acc[0], rl);
        atomicAdd(&acc[1], rf);
        atomicAdd(&spos_b[b], rp);
        atomicAdd(&sneg_b[b], rn);
        atomicAdd(&npos_b[b], (int)rc);
    }
}

// One block per batch. Common path: O(1). Rare path: top-K via bit binary search.
__global__ __launch_bounds__(256) void k_batch(
    const float* __restrict__ ce, const int* __restrict__ conf_t,
    const int* __restrict__ npos_b, const float* __restrict__ spos_b,
    const float* __restrict__ sneg_b, float* __restrict__ loss_c_b)
{
    const int b = blockIdx.x;
    const int t = threadIdx.x;
    const int npos    = npos_b[b];
    const int nneg    = NP - npos;
    const int num_neg = min(3 * npos, NP - 1);

    if (num_neg >= nneg) {              // all negatives selected (this dataset)
        if (t == 0) loss_c_b[b] = spos_b[b] + sneg_b[b];
        return;
    }
    if (num_neg <= 0) {
        if (t == 0) loss_c_b[b] = spos_b[b];
        return;
    }

    __shared__ float ce_s[NP];          // negative CE; positives -> -1
    __shared__ float sredf[4];
    __shared__ int   sredi[4];
    const float* crow = ce + (size_t)b * NP;
    const int*   trow = conf_t + (size_t)b * NP;
    for (int p = t; p < NP; p += 256)
        ce_s[p] = (trow[p] > 0) ? -1.0f : crow[p];
    __syncthreads();

    const int wave = t >> 6, lane = t & 63;
    const int K = num_neg;
    unsigned lo = 0u, hi = 0x7f800000u;
    while (lo < hi) {
        unsigned mid = lo + ((hi - lo) >> 1);
        float v = __uint_as_float(mid);
        int c_t = 0;
        for (int p = t; p < NP; p += 256) c_t += (ce_s[p] > v) ? 1 : 0;
        #pragma unroll
        for (int o = 32; o; o >>= 1) c_t += __shfl_xor(c_t, o, 64);
        __syncthreads();
        if (lane == 0) sredi[wave] = c_t;
        __syncthreads();
        int cnt = sredi[0] + sredi[1] + sredi[2] + sredi[3];
        if (cnt < K) hi = mid; else lo = mid + 1;
    }
    float v = __uint_as_float(lo);       // K-th largest negative CE
    int c_t = 0; float s_t = 0.0f;
    for (int p = t; p < NP; p += 256) {
        float x = ce_s[p];
        if (x > v) { c_t++; s_t += x; }
    }
    #pragma unroll
    for (int o = 32; o; o >>= 1) {
        c_t += __shfl_xor(c_t, o, 64);
        s_t += __shfl_xor(s_t, o, 64);
    }
    __syncthreads();
    if (lane == 0) { sredi[wave] = c_t; sredf[wave] = s_t; }
    __syncthreads();
    if (t == 0) {
        int   cnt = sredi[0] + sredi[1] + sredi[2] + sredi[3];
        float sgt = sredf[0] + sredf[1] + sredf[2] + sredf[3];
        loss_c_b[b] = spos_b[b] + sgt + (float)(K - cnt) * v;
    }
}

__global__ void k_final(const float* __restrict__ acc,
                        const float* __restrict__ loss_c_b,
                        const int* __restrict__ npos_b,
                        float* __restrict__ out)
{
    const int t = threadIdx.x;           // 64 threads
    float lc = loss_c_b[t];
    int   np = npos_b[t];
    #pragma unroll
    for (int o = 32; o; o >>= 1) {
        lc += __shfl_xor(lc, o, 64);
        np += __shfl_xor(np, o, 64);
    }
    if (t == 0) {
        float N = (float)np;
        out[0] = acc[0] / N;
        out[1] = lc / N;
        out[2] = acc[1] / N;
    }
}

extern "C" void kernel_launch(void* const* d_in, const int* in_sizes, int n_in,
                              void* d_out, int out_size, void* d_ws, size_t ws_size,
                              hipStream_t stream)
{
    const float* loc_data  = (const float*)d_in[0];
    const float* conf_data = (const float*)d_in[1];
    const float* fc_data   = (const float*)d_in[2];
    const float* loc_t     = (const float*)d_in[3];
    const float* fc_t      = (const float*)d_in[4];
    const int*   conf_t    = (const int*)d_in[5];
    float* out = (float*)d_out;

    float* ce       = (float*)d_ws;
    float* acc      = ce + BP;           // [2]
    int*   npos_b   = (int*)(acc + 2);   // [64]
    float* spos_b   = (float*)(npos_b + 64);
    float* sneg_b   = spos_b + 64;
    float* loss_c_b = sneg_b + 64;

    hipLaunchKernelGGL(k_init,  dim3(1), dim3(256), 0, stream, acc);
    hipLaunchKernelGGL(k_main,  dim3(TPB, NB), dim3(256), 0, stream,
                       loc_data, conf_data, fc_data, loc_t, fc_t, conf_t,
                       ce, acc, npos_b, spos_b, sneg_b);
    hipLaunchKernelGGL(k_batch, dim3(NB), dim3(256), 0, stream,
                       ce, conf_t, npos_b, spos_b, sneg_b, loss_c_b);
    hipLaunchKernelGGL(k_final, dim3(1), dim3(64), 0, stream,
                       acc, loss_c_b, npos_b, out);
}

// Round 4
// 322.048 us; speedup vs baseline: 1.4880x; 1.4880x over previous
//
#include <hip/hip_runtime.h>

// MultiBoxLoss_four_corners — B=64, P=8732, C=81, NEG_POS_RATIO=3
// Outputs: (loss_l/N, loss_c/N, loss_four_corners/N) -> d_out[0..2] (f32)
//
// R4: barrier-free, LDS-free. CE via float4 over row-QUADS (4 rows = 81
// aligned float4s), one quad per lane-pair (even lane f4[0..40], odd
// f4[40..80], combine with shfl_xor(1)). loc/fc via fully-coalesced
// grid-stride float4 loops. Per-batch sums via wave dual-batch reduce +
// shallow atomics. R3's LDS/barrier structure was latency-serialized
// (269 us even when L3-resident); R2's scalar loads were L1-transaction
// bound (64 lines/inst). This cuts transactions ~8x with R2's MLP depth.

#define NB 64
#define NP 8732
#define NC 81
constexpr int BP   = NB * NP;        // 558848 rows
constexpr int NQ   = BP / 4;         // 139712 row-quads
constexpr int NT   = NQ * 2;         // 279424 threads (2 per quad)
constexpr int NBLK = NT / 64;        // 4366 wave-sized blocks, no tail
constexpr int QPB  = NP / 4;         // 2183 quads per batch

__device__ inline float sl1(float d) {
    d = fabsf(d);
    return d < 1.0f ? 0.5f * d * d : d - 0.5f;
}
__device__ inline float e4(float4 v) {
    return __expf(v.x) + __expf(v.y) + __expf(v.z) + __expf(v.w);
}

// ws: ce[BP] | acc[64] (l-slots 0..31, f-slots 32..63) | spos_b[64] | sneg_b[64]
//     | npf_b[64] | loss_c_b[64]
__global__ void k_init(float* z) {           // zero acc..npf_b = 256 floats
    z[threadIdx.x] = 0.0f;
}

__global__ __launch_bounds__(64) void k_main(
    const float* __restrict__ loc_data, const float* __restrict__ conf_data,
    const float* __restrict__ fc_data,  const float* __restrict__ loc_t,
    const float* __restrict__ fc_t,     const int* __restrict__ conf_t,
    float* __restrict__ ce, float* __restrict__ acc,
    float* __restrict__ spos_b, float* __restrict__ sneg_b, float* __restrict__ npf_b)
{
    const int lane = threadIdx.x;
    const int tid  = blockIdx.x * 64 + lane;
    const int q    = tid >> 1;               // row-quad index
    const int h    = tid & 1;                // half: 0 -> f4[0..40], 1 -> f4[40..80]

    // ---- phase A: CE over this quad's 4 rows (81 f4s, 16B-aligned) ----
    const float4* cf = (const float4*)conf_data + (size_t)q * 81;
    float s0 = 0.f, s1 = 0.f, s2 = 0.f, s3 = 0.f;
    if (h == 0) {
        float4 v;
        #pragma unroll 10
        for (int k = 0; k < 20; ++k) { v = cf[k]; s0 += e4(v); }        // e0..79 -> r0
        v = cf[20];                                                      // e80..83: 1/3
        s0 += __expf(v.x); s1 += __expf(v.y) + __expf(v.z) + __expf(v.w);
        #pragma unroll 10
        for (int k = 21; k < 40; ++k) { v = cf[k]; s1 += e4(v); }       // e84..159 -> r1
        v = cf[40];                                                      // e160..163: 2/2
        s1 += __expf(v.x) + __expf(v.y); s2 += __expf(v.z) + __expf(v.w);
    } else {
        float4 v;
        #pragma unroll 10
        for (int k = 41; k < 60; ++k) { v = cf[k]; s2 += e4(v); }       // e164..239 -> r2
        v = cf[60];                                                      // e240..243: 3/1
        s2 += __expf(v.x) + __expf(v.y) + __expf(v.z); s3 += __expf(v.w);
        #pragma unroll 10
        for (int k = 61; k < 81; ++k) { v = cf[k]; s3 += e4(v); }       // e244..323 -> r3
    }
    // combine halves across the lane pair: all four row-sums complete on both
    s0 += __shfl_xor(s0, 1, 64);
    s1 += __shfl_xor(s1, 1, 64);
    s2 += __shfl_xor(s2, 1, 64);
    s3 += __shfl_xor(s3, 1, 64);

    // this lane finalizes rows 4q + 2h, 4q + 2h + 1
    const size_t rA = (size_t)4 * q + 2 * h;
    const int2 tg = *(const int2*)(conf_t + rA);          // 8B-aligned
    const float sA = h ? s2 : s0;
    const float sB = h ? s3 : s1;
    const float ceA = __logf(sA) - conf_data[rA * NC + tg.x];
    const float ceB = __logf(sB) - conf_data[(rA + 1) * NC + tg.y];
    *(float2*)(ce + rA) = make_float2(ceA, ceB);          // 8B-aligned, coalesced
    float sp = (tg.x > 0 ? ceA : 0.f) + (tg.y > 0 ? ceB : 0.f);
    float sn = (ceA + ceB) - sp;
    float np = (float)((tg.x > 0) + (tg.y > 0));

    // ---- phase B: smooth-L1, fully coalesced grid-stride float4 ----
    float l_acc = 0.f, f_acc = 0.f;
    #pragma unroll
    for (int j = 0; j < 2; ++j) {                         // loc: BP f4s = 2*NT
        const int i = tid + j * NT;                       // f4 index == row
        float4 a = ((const float4*)loc_data)[i];
        float4 b = ((const float4*)loc_t)[i];
        float m = (conf_t[i] > 0) ? 1.f : 0.f;
        l_acc += m * (sl1(a.x - b.x) + sl1(a.y - b.y) + sl1(a.z - b.z) + sl1(a.w - b.w));
    }
    #pragma unroll
    for (int j = 0; j < 4; ++j) {                         // fc: 2*BP f4s = 4*NT
        const int i = tid + j * NT;                       // row = i >> 1
        float4 a = ((const float4*)fc_data)[i];
        float4 b = ((const float4*)fc_t)[i];
        float m = (conf_t[i >> 1] > 0) ? 1.f : 0.f;
        f_acc += m * (sl1(a.x - b.x) + sl1(a.y - b.y) + sl1(a.z - b.z) + sl1(a.w - b.w));
    }

    // ---- wave reduce; a wave spans at most 2 consecutive batches ----
    const int b_ = q / QPB;
    const int b0 = __shfl(b_, 0, 64);
    const int bL = __shfl(b_, 63, 64);
    const float m0 = (b_ == b0) ? 1.f : 0.f;
    float sp0 = sp * m0, sp1 = sp - sp0;
    float sn0 = sn * m0, sn1 = sn - sn0;
    float np0 = np * m0, np1 = np - np0;
    #pragma unroll
    for (int o = 32; o; o >>= 1) {
        l_acc += __shfl_xor(l_acc, o, 64);
        f_acc += __shfl_xor(f_acc, o, 64);
        sp0 += __shfl_xor(sp0, o, 64);
        sp1 += __shfl_xor(sp1, o, 64);
        sn0 += __shfl_xor(sn0, o, 64);
        sn1 += __shfl_xor(sn1, o, 64);
        np0 += __shfl_xor(np0, o, 64);
        np1 += __shfl_xor(np1, o, 64);
    }
    if (lane == 0) {
        const int slot = blockIdx.x & 31;
        atomicAdd(&acc[slot],      l_acc);
        atomicAdd(&acc[32 + slot], f_acc);
        atomicAdd(&spos_b[b0], sp0);
        atomicAdd(&sneg_b[b0], sn0);
        atomicAdd(&npf_b[b0],  np0);
        if (bL != b0) {
            atomicAdd(&spos_b[bL], sp1);
            atomicAdd(&sneg_b[bL], sn1);
            atomicAdd(&npf_b[bL],  np1);
        }
    }
}

// One block per batch. Common path O(1); rare top-K via float-bit binary search.
__global__ __launch_bounds__(256) void k_batch(
    const float* __restrict__ ce, const int* __restrict__ conf_t,
    const float* __restrict__ npf_b, const float* __restrict__ spos_b,
    const float* __restrict__ sneg_b, float* __restrict__ loss_c_b)
{
    const int b = blockIdx.x;
    const int t = threadIdx.x;
    const int npos    = (int)(npf_b[b] + 0.5f);
    const int nneg    = NP - npos;
    const int num_neg = min(3 * npos, NP - 1);

    if (num_neg >= nneg) {                   // all negatives selected (this data)
        if (t == 0) loss_c_b[b] = spos_b[b] + sneg_b[b];
        return;
    }
    if (num_neg <= 0) {
        if (t == 0) loss_c_b[b] = spos_b[b];
        return;
    }

    __shared__ float ce_s[NP];               // negative CE; positives -> -1
    __shared__ float sredf[4];
    __shared__ int   sredi[4];
    const float* crow = ce + (size_t)b * NP;
    const int*   trow = conf_t + (size_t)b * NP;
    for (int p = t; p < NP; p += 256)
        ce_s[p] = (trow[p] > 0) ? -1.0f : crow[p];
    __syncthreads();

    const int wave = t >> 6, lane = t & 63;
    const int K = num_neg;
    unsigned lo = 0u, hi = 0x7f800000u;
    while (lo < hi) {
        unsigned mid = lo + ((hi - lo) >> 1);
        float v = __uint_as_float(mid);
        int c_t = 0;
        for (int p = t; p < NP; p += 256) c_t += (ce_s[p] > v) ? 1 : 0;
        #pragma unroll
        for (int o = 32; o; o >>= 1) c_t += __shfl_xor(c_t, o, 64);
        __syncthreads();
        if (lane == 0) sredi[wave] = c_t;
        __syncthreads();
        int cnt = sredi[0] + sredi[1] + sredi[2] + sredi[3];
        if (cnt < K) hi = mid; else lo = mid + 1;
    }
    float v = __uint_as_float(lo);           // K-th largest negative CE
    int c_t = 0; float s_t = 0.0f;
    for (int p = t; p < NP; p += 256) {
        float x = ce_s[p];
        if (x > v) { c_t++; s_t += x; }
    }
    #pragma unroll
    for (int o = 32; o; o >>= 1) {
        c_t += __shfl_xor(c_t, o, 64);
        s_t += __shfl_xor(s_t, o, 64);
    }
    __syncthreads();
    if (lane == 0) { sredi[wave] = c_t; sredf[wave] = s_t; }
    __syncthreads();
    if (t == 0) {
        int   cnt = sredi[0] + sredi[1] + sredi[2] + sredi[3];
        float sgt = sredf[0] + sredf[1] + sredf[2] + sredf[3];
        loss_c_b[b] = spos_b[b] + sgt + (float)(K - cnt) * v;
    }
}

__global__ void k_final(const float* __restrict__ acc,
                        const float* __restrict__ loss_c_b,
                        const float* __restrict__ npf_b,
                        float* __restrict__ out)
{
    const int t = threadIdx.x;               // 64
    const float av = acc[t];
    float a0 = (t < 32) ? av : 0.0f;         // l-slots
    float a1 = av - a0;                      // f-slots
    float lc = loss_c_b[t];
    float np = npf_b[t];
    #pragma unroll
    for (int o = 32; o; o >>= 1) {
        a0 += __shfl_xor(a0, o, 64);
        a1 += __shfl_xor(a1, o, 64);
        lc += __shfl_xor(lc, o, 64);
        np += __shfl_xor(np, o, 64);
    }
    if (t == 0) {
        out[0] = a0 / np;
        out[1] = lc / np;
        out[2] = a1 / np;
    }
}

extern "C" void kernel_launch(void* const* d_in, const int* in_sizes, int n_in,
                              void* d_out, int out_size, void* d_ws, size_t ws_size,
                              hipStream_t stream)
{
    const float* loc_data  = (const float*)d_in[0];
    const float* conf_data = (const float*)d_in[1];
    const float* fc_data   = (const float*)d_in[2];
    const float* loc_t     = (const float*)d_in[3];
    const float* fc_t      = (const float*)d_in[4];
    const int*   conf_t    = (const int*)d_in[5];
    float* out = (float*)d_out;

    float* ce       = (float*)d_ws;
    float* acc      = ce + BP;               // [64]
    float* spos_b   = acc + 64;              // [64]
    float* sneg_b   = spos_b + 64;           // [64]
    float* npf_b    = sneg_b + 64;           // [64]
    float* loss_c_b = npf_b + 64;            // [64]

    hipLaunchKernelGGL(k_init,  dim3(1),    dim3(256), 0, stream, acc);
    hipLaunchKernelGGL(k_main,  dim3(NBLK), dim3(64),  0, stream,
                       loc_data, conf_data, fc_data, loc_t, fc_t, conf_t,
                       ce, acc, spos_b, sneg_b, npf_b);
    hipLaunchKernelGGL(k_batch, dim3(NB),   dim3(256), 0, stream,
                       ce, conf_t, npf_b, spos_b, sneg_b, loss_c_b);
    hipLaunchKernelGGL(k_final, dim3(1),    dim3(64),  0, stream,
                       acc, loss_c_b, npf_b, out);
}